// Round 1
// baseline (563.711 us; speedup 1.0000x reference)
//
#include <hip/hip_runtime.h>
#include <math.h>

// Problem constants (CBOW_5205500363137)
#define BB     65536
#define KK     10
#define EE     128
#define NBLK   2048   // main-kernel grid
#define ITERS  4      // row-groups per block: 2048 * 4 * 8 rows = 65536

__device__ __forceinline__ float log_sigmoid_f(float x) {
    // log(sigmoid(x)) = min(x, 0) - log1p(exp(-|x|))   (numerically stable)
    return fminf(x, 0.0f) - log1pf(expf(-fabsf(x)));
}

__global__ __launch_bounds__(256) void cbow_main(
    const int*   __restrict__ ctx_words,   // [B]
    const int*   __restrict__ tgt_words,   // [B]
    const int*   __restrict__ neg_words,   // [B,K]
    const float* __restrict__ V_emb,       // [VOCAB,E]
    const float* __restrict__ U_emb,       // [VOCAB,E]
    const float* __restrict__ mask_v,      // [B,E]
    const float* __restrict__ mask_u,      // [B,E]
    const float* __restrict__ mask_neg,    // [B,K,E]
    double*      __restrict__ partials)    // [NBLK]
{
    const int t    = threadIdx.x;
    const int sub  = t >> 5;    // 0..7: half-wave id within block (one row each)
    const int lane = t & 31;    // lane within the 32-lane half-wave

    double local = 0.0;         // per-leader accumulation across ITERS

    for (int gi = 0; gi < ITERS; ++gi) {
        const int row = (blockIdx.x * ITERS + gi) * 8 + sub;

        const int ctx = ctx_words[row];
        const int tgt = tgt_words[row];

        // v = V_emb[ctx] * mask_v[row]   (each lane holds 4 consecutive floats)
        const float4 ve = ((const float4*)(V_emb   + (size_t)ctx * EE))[lane];
        const float4 mv = ((const float4*)(mask_v  + (size_t)row * EE))[lane];
        float4 v;
        v.x = ve.x * mv.x; v.y = ve.y * mv.y; v.z = ve.z * mv.z; v.w = ve.w * mv.w;

        // u = U_emb[tgt] * mask_u[row]; pos partial = dot(u, v)
        const float4 ue = ((const float4*)(U_emb   + (size_t)tgt * EE))[lane];
        const float4 mu = ((const float4*)(mask_u  + (size_t)row * EE))[lane];
        float posp = 0.0f;
        posp = fmaf(ue.x * mu.x, v.x, posp);
        posp = fmaf(ue.y * mu.y, v.y, posp);
        posp = fmaf(ue.z * mu.z, v.z, posp);
        posp = fmaf(ue.w * mu.w, v.w, posp);

        // Preload the 10 negative indices (contiguous 40 B)
        int nk[KK];
#pragma unroll
        for (int k = 0; k < KK; ++k) nk[k] = neg_words[(size_t)row * KK + k];

        // negp = sum_k dot(U_emb[nk]*mask_neg[row,k], v);  neg_score = -negp
        float negp = 0.0f;
#pragma unroll
        for (int k = 0; k < KK; ++k) {
            const float4 ne = ((const float4*)(U_emb + (size_t)nk[k] * EE))[lane];
            const float4 mn = ((const float4*)(mask_neg + ((size_t)row * KK + k) * EE))[lane];
            negp = fmaf(ne.x * mn.x, v.x, negp);
            negp = fmaf(ne.y * mn.y, v.y, negp);
            negp = fmaf(ne.z * mn.z, v.z, negp);
            negp = fmaf(ne.w * mn.w, v.w, negp);
        }

        // Reduce within the 32-lane half (xor masks <=16 stay inside each half)
        float pos = posp, neg = negp;
#pragma unroll
        for (int m = 16; m >= 1; m >>= 1) {
            pos += __shfl_xor(pos, m, 64);
            neg += __shfl_xor(neg, m, 64);
        }

        if (lane == 0) {
            const float loss = log_sigmoid_f(pos) + log_sigmoid_f(-neg);
            local += (double)loss;
        }
    }

    // Block reduction: 8 half-wave leaders -> one double per block
    __shared__ double sbuf[8];
    if (lane == 0) sbuf[sub] = local;
    __syncthreads();
    if (t == 0) {
        double s = 0.0;
#pragma unroll
        for (int i = 0; i < 8; ++i) s += sbuf[i];
        partials[blockIdx.x] = s;
    }
}

__global__ __launch_bounds__(256) void cbow_reduce(
    const double* __restrict__ partials, float* __restrict__ out)
{
    __shared__ double sbuf[256];
    double s = 0.0;
    for (int i = threadIdx.x; i < NBLK; i += 256) s += partials[i];
    sbuf[threadIdx.x] = s;
    __syncthreads();
    for (int stride = 128; stride > 0; stride >>= 1) {
        if (threadIdx.x < stride) sbuf[threadIdx.x] += sbuf[threadIdx.x + stride];
        __syncthreads();
    }
    if (threadIdx.x == 0) out[0] = (float)(-sbuf[0] / (double)BB);
}

extern "C" void kernel_launch(void* const* d_in, const int* in_sizes, int n_in,
                              void* d_out, int out_size, void* d_ws, size_t ws_size,
                              hipStream_t stream) {
    const int*   ctx_words = (const int*)  d_in[0];
    const int*   tgt_words = (const int*)  d_in[1];
    const int*   neg_words = (const int*)  d_in[2];
    const float* V_emb     = (const float*)d_in[3];
    const float* U_emb     = (const float*)d_in[4];
    const float* mask_v    = (const float*)d_in[5];
    const float* mask_u    = (const float*)d_in[6];
    const float* mask_neg  = (const float*)d_in[7];
    float*       out       = (float*)d_out;
    double*      partials  = (double*)d_ws;   // needs NBLK*8 = 16 KiB of ws

    cbow_main<<<NBLK, 256, 0, stream>>>(ctx_words, tgt_words, neg_words,
                                        V_emb, U_emb, mask_v, mask_u, mask_neg,
                                        partials);
    cbow_reduce<<<1, 256, 0, stream>>>(partials, out);
}

// Round 2
// 549.551 us; speedup vs baseline: 1.0258x; 1.0258x over previous
//
#include <hip/hip_runtime.h>
#include <math.h>

// Problem constants (CBOW_5205500363137)
#define BB     65536
#define KK     10
#define EE     128
#define NBLK   2048   // main-kernel grid
#define ITERS  4      // row-groups per block: 2048 * 4 * 8 rows = 65536

typedef float f4 __attribute__((ext_vector_type(4)));

// Non-temporal 16B load (streaming data: dropout masks are use-once; keep L2
// for the V/U embedding tables which are gathered randomly and re-used).
__device__ __forceinline__ f4 ldnt(const float* p) {
    return __builtin_nontemporal_load((const f4*)p);
}
__device__ __forceinline__ f4 ldg4(const float* p) {
    return *(const f4*)p;
}

__device__ __forceinline__ float log_sigmoid_f(float x) {
    // log(sigmoid(x)) = min(x, 0) - log1p(exp(-|x|))   (numerically stable)
    return fminf(x, 0.0f) - log1pf(expf(-fabsf(x)));
}

__global__ __launch_bounds__(256) void cbow_main(
    const int*   __restrict__ ctx_words,   // [B]
    const int*   __restrict__ tgt_words,   // [B]
    const int*   __restrict__ neg_words,   // [B,K]
    const float* __restrict__ V_emb,       // [VOCAB,E]
    const float* __restrict__ U_emb,       // [VOCAB,E]
    const float* __restrict__ mask_v,      // [B,E]
    const float* __restrict__ mask_u,      // [B,E]
    const float* __restrict__ mask_neg,    // [B,K,E]
    double*      __restrict__ partials)    // [NBLK]
{
    const int t    = threadIdx.x;
    const int sub  = t >> 5;    // 0..7: half-wave id within block (one row each)
    const int lane = t & 31;    // lane within the 32-lane half-wave

    double local = 0.0;         // per-leader accumulation across ITERS

    for (int gi = 0; gi < ITERS; ++gi) {
        const int row = (blockIdx.x * ITERS + gi) * 8 + sub;

        const int ctx = ctx_words[row];
        const int tgt = tgt_words[row];
        // One load for the 10 negative indices: lanes 0..9 each load one,
        // broadcast later via shfl (width 32 keeps it inside the half-wave).
        const int nidx = neg_words[(size_t)row * KK + (lane < KK ? lane : 0)];

        // v = V_emb[ctx] * mask_v[row]   (each lane holds 4 consecutive floats)
        const f4 ve = ldg4(V_emb  + (size_t)ctx * EE + lane * 4);
        const f4 mv = ldnt(mask_v + (size_t)row * EE + lane * 4);
        const f4 v  = ve * mv;

        // u = U_emb[tgt] * mask_u[row]; pos partial = dot(u, v)
        const f4 ue = ldg4(U_emb  + (size_t)tgt * EE + lane * 4);
        const f4 mu = ldnt(mask_u + (size_t)row * EE + lane * 4);
        const f4 up = ue * mu;
        float posp = fmaf(up.x, v.x, fmaf(up.y, v.y, fmaf(up.z, v.z, up.w * v.w)));

        // negp = sum_k dot(U_emb[nk]*mask_neg[row,k], v);  neg_score = -negp
        float negp = 0.0f;
#pragma unroll
        for (int k = 0; k < KK; ++k) {
            const int nk = __shfl(nidx, k, 32);
            const f4 ne = ldg4(U_emb + (size_t)nk * EE + lane * 4);
            const f4 mn = ldnt(mask_neg + ((size_t)row * KK + k) * EE + lane * 4);
            const f4 np = ne * mn;
            negp = fmaf(np.x, v.x, negp);
            negp = fmaf(np.y, v.y, negp);
            negp = fmaf(np.z, v.z, negp);
            negp = fmaf(np.w, v.w, negp);
        }

        // Reduce within the 32-lane half (xor masks <=16 stay inside each half)
        float pos = posp, neg = negp;
#pragma unroll
        for (int m = 16; m >= 1; m >>= 1) {
            pos += __shfl_xor(pos, m, 64);
            neg += __shfl_xor(neg, m, 64);
        }

        if (lane == 0) {
            const float loss = log_sigmoid_f(pos) + log_sigmoid_f(-neg);
            local += (double)loss;
        }
    }

    // Block reduction: 8 half-wave leaders -> one double per block
    __shared__ double sbuf[8];
    if (lane == 0) sbuf[sub] = local;
    __syncthreads();
    if (t == 0) {
        double s = 0.0;
#pragma unroll
        for (int i = 0; i < 8; ++i) s += sbuf[i];
        partials[blockIdx.x] = s;
    }
}

__global__ __launch_bounds__(256) void cbow_reduce(
    const double* __restrict__ partials, float* __restrict__ out)
{
    __shared__ double sbuf[256];
    double s = 0.0;
    for (int i = threadIdx.x; i < NBLK; i += 256) s += partials[i];
    sbuf[threadIdx.x] = s;
    __syncthreads();
    for (int stride = 128; stride > 0; stride >>= 1) {
        if (threadIdx.x < stride) sbuf[threadIdx.x] += sbuf[threadIdx.x + stride];
        __syncthreads();
    }
    if (threadIdx.x == 0) out[0] = (float)(-sbuf[0] / (double)BB);
}

extern "C" void kernel_launch(void* const* d_in, const int* in_sizes, int n_in,
                              void* d_out, int out_size, void* d_ws, size_t ws_size,
                              hipStream_t stream) {
    const int*   ctx_words = (const int*)  d_in[0];
    const int*   tgt_words = (const int*)  d_in[1];
    const int*   neg_words = (const int*)  d_in[2];
    const float* V_emb     = (const float*)d_in[3];
    const float* U_emb     = (const float*)d_in[4];
    const float* mask_v    = (const float*)d_in[5];
    const float* mask_u    = (const float*)d_in[6];
    const float* mask_neg  = (const float*)d_in[7];
    float*       out       = (float*)d_out;
    double*      partials  = (double*)d_ws;   // needs NBLK*8 = 16 KiB of ws

    cbow_main<<<NBLK, 256, 0, stream>>>(ctx_words, tgt_words, neg_words,
                                        V_emb, U_emb, mask_v, mask_u, mask_neg,
                                        partials);
    cbow_reduce<<<1, 256, 0, stream>>>(partials, out);
}